// Round 7
// baseline (478.658 us; speedup 1.0000x reference)
//
#include <hip/hip_runtime.h>
#include <hip/hip_bf16.h>

// PointCloudNetPersistencePrediction — round 26: 256-thr / M=16 / 4-way
// k-split apply with wave0-resident epilogue. R25's traffic cut was
// invisible -> per-apply = eval-issue (~7us) + boundary (~7-8us) + epilogue
// (~1.5-2us). This round attacks the epilogue: waves 1-3 dump 3KB partials,
// wave 0 reduces IN REGISTERS and does the whole epilogue from its MFMA
// C-layout (lane = col n, 4 consecutive rows -> half4/float4 stores, no
// second LDS round-trip; deg via 4 shfls). LDS 19.5KB -> 8 blocks/CU x 4
// waves = 32 waves/CU full occupancy, one clean 2048-block round (finer
// drain than 1024x512). R22's failure of this shape was global-Xp-in-loop;
// per-wave LDS slice staging is kept (R21/R22 lesson: eval operands must be
// LDS/register). Numerics: k-grouping 8x256 -> 4x512 (f32 add-order only).
// MODE: 0=STEP1(fused init) 1=P1 2=P1+BUILDU 3=P2 4=P2TAIL 5=FUSEDRED

#define NN 2048
#define NPAIR 16

typedef _Float16 half8 __attribute__((ext_vector_type(8)));
typedef _Float16 half4 __attribute__((ext_vector_type(4)));
typedef _Float16 f16x2 __attribute__((ext_vector_type(2)));
typedef float f32x4 __attribute__((ext_vector_type(4)));

extern "C" __device__ f16x2 __ocml_exp2_2f16(f16x2);   // 2x v_exp_f16

#define C2F 0.28853900817779268f   //  0.2 * log2(e)
#define CWF -0.14426950408889634f  // -0.1 * log2(e)
#define NL2T 3.3219280948873623f   // -log2(0.1); qi' = qi + NL2T

template<int MODE>
__global__ __launch_bounds__(256, 8)
void apply_k(const float* __restrict__ pc, const float* __restrict__ alphas,
             float* __restrict__ Xs, _Float16* __restrict__ Xp,
             float* __restrict__ ihd,
             const _Float16* __restrict__ cur, _Float16* __restrict__ out,
             float* __restrict__ lvl, int t,
             const float* __restrict__ LT1u, const float* __restrict__ LT2r,
             float* __restrict__ fout) {
    // [0..4095]    : staged j-pair entries (1024 float4 = 16KB)
    // [4096..4863] : waves 1-3 partials (3KB); reused post-reduce as the
    //                BUILDU (3x16) / FUSEDRED (12x16) stash
    __shared__ __align__(16) float smem[4864];
    const int tid  = threadIdx.x;
    const int lane = tid & 63;
    const int wv   = tid >> 6;                     // k-quarter 0..3
    const int p    = blockIdx.y;
    const int m0   = blockIdx.x * 16;
    const int idx16 = lane & 15, quad = lane >> 4;
    const int b = p >> 2;

    float a0, a1, a2;
    if (MODE == 0) {
        const int kk = p & 3;
        a0 = alphas[kk * 3 + 0]; a1 = alphas[kk * 3 + 1]; a2 = alphas[kk * 3 + 2];
        if (blockIdx.x == 0 && tid < 48) fout[p * 48 + tid] = 0.f;
        // compute own k-quarter's 256 j-pair entries from pc*alphas
        float4* dst = (float4*)smem;
#pragma unroll
        for (int e = 0; e < 4; ++e) {
            const int idx = wv * 256 + e * 64 + lane;
            const float* r = pc + ((size_t)b * NN + idx * 2) * 3;  // 2 points
            float x0 = r[0] * a0, y0 = r[1] * a1, z0 = r[2] * a2;
            float x1 = r[3] * a0, y1 = r[4] * a1, z1 = r[5] * a2;
            float q0 = CWF * (x0 * x0 + y0 * y0 + z0 * z0);
            float q1 = CWF * (x1 * x1 + y1 * y1 + z1 * z1);
            union { float4 f; f16x2 h[4]; } ev;
            ev.h[0] = (f16x2){(_Float16)x0, (_Float16)x1};
            ev.h[1] = (f16x2){(_Float16)y0, (_Float16)y1};
            ev.h[2] = (f16x2){(_Float16)z0, (_Float16)z1};
            ev.h[3] = (f16x2){(_Float16)q0, (_Float16)q1};
            dst[idx] = ev.f;
            if (blockIdx.x == 0) ((float4*)Xp)[(size_t)p * 1024 + idx] = ev.f;
        }
    } else {
        // per-wave slice staging (wave reads only its own 256 entries)
        const float4* src = (const float4*)(Xp + (size_t)p * 8192);
        float4* dst = (float4*)smem;
#pragma unroll
        for (int e = 0; e < 4; ++e)
            dst[wv * 256 + e * 64 + lane] = src[wv * 256 + e * 64 + lane];
    }

    f16x2 qi2, xx2, xy2, xz2;
    {
        const int row = m0 + idx16;
        float fx, fy, fz, fq;
        if (MODE == 0) {
            const float* r = pc + ((size_t)b * NN + row) * 3;
            fx = r[0] * a0; fy = r[1] * a1; fz = r[2] * a2;
            fq = CWF * (fx * fx + fy * fy + fz * fz);
            if (wv == 0 && quad == 0) {
                float4 o; o.x = fx; o.y = fy; o.z = fz; o.w = fq;
                *(float4*)(Xs + ((size_t)p * NN + row) * 4) = o;
            }
        } else {
            float4 v = *(const float4*)(Xs + ((size_t)p * NN + row) * 4);
            fx = v.x; fy = v.y; fz = v.z; fq = v.w;
        }
        _Float16 q = (_Float16)(fq + NL2T);
        _Float16 x = (_Float16)(C2F * fx);
        _Float16 y = (_Float16)(C2F * fy);
        _Float16 z = (_Float16)(C2F * fz);
        qi2 = (f16x2){q, q}; xx2 = (f16x2){x, x};
        xy2 = (f16x2){y, y}; xz2 = (f16x2){z, z};
    }
    const f16x2 SC2  = (f16x2){(_Float16)32768.f, (_Float16)32768.f};
    const f16x2 ONE2 = (f16x2){(_Float16)1.f, (_Float16)1.f};
    const f16x2 ZER2 = (f16x2){(_Float16)0.f, (_Float16)0.f};

    const _Float16* bp = cur + ((size_t)p * 16 + idx16) * NN + wv * 512 + quad * 8;
    f32x4 acc = {0.f, 0.f, 0.f, 0.f};

    for (int kc = 0; kc < 16; ++kc) {
        const int pb = wv * 256 + kc * 16 + quad * 4;  // j-pair entry base
        union { f16x2 h2[4]; half8 h8; } bfu;
        if (MODE != 0) {
            bool ld;
            if (MODE == 3)                   ld = true;
            else if (MODE == 1 || MODE == 2) ld = (idx16 < 3);
            else                             ld = (idx16 >= 4);   // 4,5 (row3=0)
            if (ld) bfu.h8 = *(const half8*)(bp + kc * 32);
            else {
#pragma unroll
                for (int z = 0; z < 4; ++z) bfu.h2[z] = ZER2;
            }
        }
        union { f16x2 h2[4]; half8 h8; } af;
#pragma unroll
        for (int jp = 0; jp < 4; ++jp) {
            union { float4 f; f16x2 h[4]; } e;
            e.f = ((const float4*)smem)[pb + jp];      // {x2,y2,z2,q2} for 2 j
            if (MODE == 0) {                           // B = {x,y,z,1,0..} in-reg
                bfu.h2[jp] = (idx16 == 0) ? e.h[0]
                           : (idx16 == 1) ? e.h[1]
                           : (idx16 == 2) ? e.h[2]
                           : (idx16 == 3) ? ONE2 : ZER2;
            }
            f16x2 tv = qi2 + e.h[3];
            tv = __builtin_elementwise_fma(xx2, e.h[0], tv);
            tv = __builtin_elementwise_fma(xy2, e.h[1], tv);
            tv = __builtin_elementwise_fma(xz2, e.h[2], tv);
            // threshold folded into exp arg: t'<0 -> arg<=-24 -> exp2 = 0
            f16x2 u = __builtin_elementwise_min(tv, tv * SC2);
            af.h2[jp] = __ocml_exp2_2f16(u);           // = 10*w (2^3.32 fold)
        }
        acc = __builtin_amdgcn_mfma_f32_16x16x32_f16(af.h8, bfu.h8, acc, 0, 0, 0);
    }

    // ---- waves 1-3: dump partials; wave 0: reduce in-register ----
    if (wv != 0)
        *(f32x4*)&smem[4096 + (wv - 1) * 256 + lane * 4] = acc;
    __syncthreads();

    // wave 0 owns the 16x16 output tile: lane -> col n=idx16, rows r0..r0+3
    const int n  = idx16;
    const int r0 = m0 + quad * 4;
    float o1v[4], ihq[4];
    if (wv == 0) {
#pragma unroll
        for (int g = 0; g < 3; ++g)
            acc += *(const f32x4*)&smem[4096 + g * 256 + lane * 4];
        if (MODE == 0) {
#pragma unroll
            for (int j = 0; j < 4; ++j) {
                float deg10 = __shfl(acc[j], quad * 16 + 3, 64);  // col3 = 10*deg
                ihq[j] = 5.0f / deg10;                            // = 0.5/deg
            }
            if (n == 3) {
                float4 iv; iv.x = ihq[0]; iv.y = ihq[1]; iv.z = ihq[2]; iv.w = ihq[3];
                *(float4*)(ihd + (size_t)p * NN + r0) = iv;
            }
        } else {
            float4 iv = *(const float4*)(ihd + (size_t)p * NN + r0);
            ihq[0] = iv.x; ihq[1] = iv.y; ihq[2] = iv.z; ihq[3] = iv.w;
        }
        float cv[4];
        if (MODE == 0) {
#pragma unroll
            for (int j = 0; j < 4; ++j)
                cv[j] = (n < 3) ? pc[((size_t)b * NN + r0 + j) * 3 + n]
                                  * (n == 0 ? a0 : (n == 1 ? a1 : a2))
                                : 0.f;
        } else {
            half4 cvv = *(const half4*)(cur + ((size_t)p * 16 + n) * NN + r0);
#pragma unroll
            for (int j = 0; j < 4; ++j) {
                bool live;
                if (MODE == 1 || MODE == 2) live = (n < 3);
                else if (MODE == 3)         live = true;
                else                        live = (n >= 4);
                cv[j] = live ? (float)cvv[j] : 0.f;
            }
        }
#pragma unroll
        for (int j = 0; j < 4; ++j)
            o1v[j] = 0.5f * cv[j] + 0.1f * ihq[j] * acc[j];
    }

    if (MODE == 0 || MODE == 1) {
        if (wv != 0) return;
        if (n < 3) {
            half4 ov = {(_Float16)o1v[0], (_Float16)o1v[1],
                        (_Float16)o1v[2], (_Float16)o1v[3]};
            *(half4*)(out + ((size_t)p * 16 + n) * NN + r0) = ov;
            if (lvl) {
                float4 lv; lv.x = o1v[0]; lv.y = o1v[1]; lv.z = o1v[2]; lv.w = o1v[3];
                *(float4*)(lvl + (((size_t)p * 5 + t) * 16 + n) * NN + r0) = lv;
            }
        }
        return;
    } else if (MODE == 3) {
        if (wv != 0) return;
        half4 ov = {(_Float16)o1v[0], (_Float16)o1v[1],
                    (_Float16)o1v[2], (_Float16)o1v[3]};
        *(half4*)(out + ((size_t)p * 16 + n) * NN + r0) = ov;
        if (lvl && (n >= 4 || (t == 3 && n < 3))) {
            float4 lv; lv.x = o1v[0]; lv.y = o1v[1]; lv.z = o1v[2]; lv.w = o1v[3];
            *(float4*)(lvl + (((size_t)p * 5 + t) * 16 + n) * NN + r0) = lv;
        }
        return;
    } else if (MODE == 4) {
        if (wv != 0) return;
        if (n >= 4) {
            half4 ov = {(_Float16)o1v[0], (_Float16)o1v[1],
                        (_Float16)o1v[2], (_Float16)o1v[3]};
            *(half4*)(out + ((size_t)p * 16 + n) * NN + r0) = ov;
        }
        return;
    } else if (MODE == 2) {
        // stash fresh t=8 cols 0-2 (partials region is consumed), bar, emit
        if (wv == 0 && n < 3) {
            float4 lv; lv.x = o1v[0]; lv.y = o1v[1]; lv.z = o1v[2]; lv.w = o1v[3];
            *(float4*)(lvl + (((size_t)p * 5 + t) * 16 + n) * NN + r0) = lv;
#pragma unroll
            for (int j = 0; j < 4; ++j) smem[4096 + n * 16 + quad * 4 + j] = o1v[j];
        }
        __syncthreads();
        if (wv != 0) return;
        float ov[4];
#pragma unroll
        for (int j = 0; j < 4; ++j) ov[j] = o1v[j];       // n<3: t8; n==3: exact 0
        if (n >= 4) {                                     // rows 4-15: U = |psi_jw|_c
            const int u = n - 4, jw = u / 3, c = u - 3 * jw;
            float av[4], bv[4];
            if (jw == 0) {
#pragma unroll
                for (int j = 0; j < 4; ++j)
                    av[j] = Xs[((size_t)p * NN + r0 + j) * 4 + c];
            } else {
                float4 t4 = *(const float4*)(LT1u + (((size_t)p * 5 + (jw - 1)) * 16 + c) * NN + r0);
                av[0] = t4.x; av[1] = t4.y; av[2] = t4.z; av[3] = t4.w;
            }
            if (jw == 3) {
#pragma unroll
                for (int j = 0; j < 4; ++j)
                    bv[j] = smem[4096 + c * 16 + quad * 4 + j];
            } else {
                float4 t4 = *(const float4*)(LT1u + (((size_t)p * 5 + jw) * 16 + c) * NN + r0);
                bv[0] = t4.x; bv[1] = t4.y; bv[2] = t4.z; bv[3] = t4.w;
            }
#pragma unroll
            for (int j = 0; j < 4; ++j) ov[j] = fabsf(av[j] - bv[j]);
        }
        half4 o = {(_Float16)ov[0], (_Float16)ov[1], (_Float16)ov[2], (_Float16)ov[3]};
        *(half4*)(out + ((size_t)p * 16 + n) * NN + r0) = o;
        return;
    } else {                                              // MODE 5: fused reduction
        if (wv == 0 && n >= 4) {
#pragma unroll
            for (int j = 0; j < 4; ++j)
                smem[4096 + (n - 4) * 16 + quad * 4 + j] = o1v[j];  // slot4 r4-15
        }
        __syncthreads();
        if (tid < 192) {
            const int f = tid >> 2, g = tid & 3;          // 48 f x 4 thr
            const float* l1 = LT1u + (size_t)p * 5 * 16 * NN;
            const float* l2 = LT2r + (size_t)p * 5 * 16 * NN;
            float s = 0.f;
#pragma unroll
            for (int k = 0; k < 4; ++k) {
                const int m = m0 + g * 4 + k;
                float v;
                if (f < 3) {
                    v = l2[((size_t)3 * 16 + f) * NN + m];  // P^16 F (slot3 r0-2)
                } else if (f < 18) {
                    int j = (f - 3) / 3, c = (f - 3) % 3;
                    float a = (j == 0) ? Xs[((size_t)p * NN + m) * 4 + c]
                                       : l1[((size_t)(j - 1) * 16 + c) * NN + m];
                    float bb = (j < 4) ? l1[((size_t)j * 16 + c) * NN + m]
                                       : l2[((size_t)3 * 16 + c) * NN + m];
                    v = fabsf(a - bb);
                } else {
                    int gg = f - 18, j2, uc;
                    if (gg < 3)       { j2 = 1; uc = gg; }
                    else if (gg < 9)  { j2 = 2; uc = gg - 3; }
                    else if (gg < 18) { j2 = 3; uc = gg - 9; }
                    else              { j2 = 4; uc = gg - 18; }
                    float a = l2[((size_t)(j2 - 1) * 16 + uc + 4) * NN + m];
                    float bb = (j2 == 4) ? smem[4096 + uc * 16 + (g * 4 + k)]
                                         : l2[((size_t)j2 * 16 + uc + 4) * NN + m];
                    v = fabsf(a - bb);
                }
                s += v;
            }
#pragma unroll
            for (int off = 2; off > 0; off >>= 1) s += __shfl_down(s, off, 4);
            if (g == 0) atomicAdd(&fout[p * 48 + f], s * (1.0f / NN));
        }
        return;
    }
}

extern "C" void kernel_launch(void* const* d_in, const int* in_sizes, int n_in,
                              void* d_out, int out_size, void* d_ws, size_t ws_size,
                              hipStream_t stream) {
    const float* pc     = (const float*)d_in[0];
    const float* alphas = (const float*)d_in[1];
    float* outp = (float*)d_out;

    char* base = (char*)d_ws;
    size_t off = 0;
    auto carve = [&](size_t bytes) -> void* {
        void* r = base + off;
        off = (off + bytes + 255) & ~(size_t)255;
        return r;
    };
    float*     Xs  = (float*)carve((size_t)NPAIR * NN * 4 * sizeof(float));
    _Float16*  Xp  = (_Float16*)carve((size_t)NPAIR * 1024 * 8 * 2);
    float*     ihd = (float*)carve((size_t)NPAIR * NN * sizeof(float));
    _Float16*  pA  = (_Float16*)carve((size_t)NPAIR * 16 * NN * 2);
    _Float16*  pB  = (_Float16*)carve((size_t)NPAIR * 16 * NN * 2);
    float*     LT1 = (float*)carve((size_t)NPAIR * 5 * 16 * NN * sizeof(float));
    float*     LT2 = (float*)carve((size_t)NPAIR * 5 * 16 * NN * sizeof(float));

    dim3 gridA(NN / 16, NPAIR);   // 128 x 16 = 2048 blocks, 8/CU

    // step 1: fused init (Xs/Xp/out-zero) + apply (t=1 -> LT1 slot 0, ihd)
    apply_k<0><<<gridA, 256, 0, stream>>>(pc, alphas, Xs, Xp, ihd,
        nullptr, pA, LT1, 0, nullptr, nullptr, outp);
    const _Float16* c1 = pA;
    int slot = 1;

    // phase 1: bank1 steps 2..8 (t=2,4,8 -> LT1 slots 1..3); step 8 packs U
    // into rows 4-15 of its output (combined bank, row 3 = 0).
    for (int step = 2; step <= 8; ++step) {
        _Float16* o1 = (c1 == pA) ? pB : pA;
        bool sv = (step & (step - 1)) == 0;
        if (step == 8)
            apply_k<2><<<gridA, 256, 0, stream>>>(pc, alphas, Xs, Xp, ihd,
                c1, o1, LT1, 3, LT1, nullptr, nullptr);
        else
            apply_k<1><<<gridA, 256, 0, stream>>>(pc, alphas, Xs, Xp, ihd,
                c1, o1, sv ? LT1 : nullptr, slot, nullptr, nullptr, nullptr);
        if (sv) ++slot;
        c1 = o1;
    }

    // phase 2: combined bank, 16 steps. saves i=1,2,4,8 -> LT2 slots 0..3
    // (slot 3 rows 0-2 = bank1 t16 low-pass). i=9..15: rows 0-2 dead.
    // i=16: fused final reduction (atomicAdd into d_out).
    int slot2 = 0;
    for (int i = 1; i <= 16; ++i) {
        _Float16* o1 = (c1 == pA) ? pB : pA;
        if (i == 16) {
            apply_k<5><<<gridA, 256, 0, stream>>>(pc, alphas, Xs, Xp, ihd,
                c1, o1, nullptr, 4, LT1, LT2, outp);
        } else if (i <= 8) {
            bool sv = (i & (i - 1)) == 0;
            apply_k<3><<<gridA, 256, 0, stream>>>(pc, alphas, Xs, Xp, ihd,
                c1, o1, sv ? LT2 : nullptr, slot2, nullptr, nullptr, nullptr);
            if (sv) ++slot2;
        } else {
            apply_k<4><<<gridA, 256, 0, stream>>>(pc, alphas, Xs, Xp, ihd,
                c1, o1, nullptr, 0, nullptr, nullptr, nullptr);
        }
        c1 = o1;
    }
}

// Round 8
// 429.155 us; speedup vs baseline: 1.1153x; 1.1153x over previous
//
#include <hip/hip_runtime.h>
#include <hip/hip_bf16.h>

// PointCloudNetPersistencePrediction — round 27: revert R26 (M=16/wave0-
// epilogue lost the s=2 register blocking: 2x ds_read + 2x B-load per eval
// and a serialized epilogue; −55us). Base = R25 (423.3us, best verified)
// with two bit-identical micro-opts:
// (1) kc loop fully unrolled -> compiler hoists/batches the 8 global half8
//     B-loads and software-pipelines the 32 ds_reads instead of exposing
//     per-iteration load latency at each loop head.
// (2) MODE 3 skips the row-3 B-load (row 3 of the combined bank is exact 0
//     from MODE 2's construction) -> zeroed register instead of loads.
// MODE: 0=STEP1(fused init) 1=P1 2=P1+BUILDU 3=P2 4=P2TAIL 5=FUSEDRED
// Lessons pinned: eval operands must be LDS/register (R21/R22); keep s=2
// blocking + 512-thr all-thread epilogue (R26); traffic/barriers not the
// limiter (R23/R25); boundary ~3.5us, in-kernel ~14us, depth-24 minimal.

#define NN 2048
#define NPAIR 16

typedef _Float16 half8 __attribute__((ext_vector_type(8)));
typedef _Float16 f16x2 __attribute__((ext_vector_type(2)));
typedef float f32x4 __attribute__((ext_vector_type(4)));

extern "C" __device__ f16x2 __ocml_exp2_2f16(f16x2);   // packed v_exp_f16

#define C2F 0.28853900817779268f   //  0.2 * log2(e)
#define CWF -0.14426950408889634f  // -0.1 * log2(e)
#define NL2T 3.3219280948873623f   // -log2(0.1); qi' = qi + NL2T

// MODE: 0=STEP1(fused init), 1=P1, 2=P1+BUILDU, 3=P2, 4=P2TAIL, 5=FUSEDRED
template<int MODE>
__global__ __launch_bounds__(512, 8)
void apply_k(const float* __restrict__ pc, const float* __restrict__ alphas,
             float* __restrict__ Xs, _Float16* __restrict__ Xp,
             float* __restrict__ ihd,
             const _Float16* __restrict__ cur, _Float16* __restrict__ out,
             float* __restrict__ lvl, int t,
             const float* __restrict__ LT1u, const float* __restrict__ LT2r,
             float* __restrict__ fout) {
    // [0..4095]   : staged j-pair entries (1024 float4)
    // [4096..8191]: 8 waves x 512 MFMA partials
    // [8192..8575]: BUILDU stash (3x32) / FUSEDRED slot4 stash (12x32)
    __shared__ __align__(16) float smem[8576];
    const int tid  = threadIdx.x;
    const int lane = tid & 63;
    const int wv   = tid >> 6;                     // K-group 0..7
    const int p    = blockIdx.y;
    const int m0   = blockIdx.x * 32;
    const int idx16 = lane & 15, quad = lane >> 4;
    const int b = p >> 2;

    float a0, a1, a2;
    if (MODE == 0) {
        const int kk = p & 3;
        a0 = alphas[kk * 3 + 0]; a1 = alphas[kk * 3 + 1]; a2 = alphas[kk * 3 + 2];
        if (blockIdx.x == 0 && tid < 48) fout[p * 48 + tid] = 0.f;
        // per-wave slice: compute own 128 j-pair entries from pc*alphas
        float4* dst = (float4*)smem;
#pragma unroll
        for (int e = 0; e < 2; ++e) {
            const int idx = wv * 128 + e * 64 + lane;
            const float* r = pc + ((size_t)b * NN + idx * 2) * 3;  // 2 points, 6 floats
            float x0 = r[0] * a0, y0 = r[1] * a1, z0 = r[2] * a2;
            float x1 = r[3] * a0, y1 = r[4] * a1, z1 = r[5] * a2;
            float q0 = CWF * (x0 * x0 + y0 * y0 + z0 * z0);
            float q1 = CWF * (x1 * x1 + y1 * y1 + z1 * z1);
            union { float4 f; f16x2 h[4]; } ev;
            ev.h[0] = (f16x2){(_Float16)x0, (_Float16)x1};
            ev.h[1] = (f16x2){(_Float16)y0, (_Float16)y1};
            ev.h[2] = (f16x2){(_Float16)z0, (_Float16)z1};
            ev.h[3] = (f16x2){(_Float16)q0, (_Float16)q1};
            dst[idx] = ev.f;
            if (blockIdx.x == 0) ((float4*)Xp)[(size_t)p * 1024 + idx] = ev.f;
        }
    } else {
        // per-wave slice staging from global Xp (no barrier needed)
        const float4* src = (const float4*)(Xp + (size_t)p * 8192);
        float4* dst = (float4*)smem;
        dst[wv * 128 + lane]      = src[wv * 128 + lane];
        dst[wv * 128 + 64 + lane] = src[wv * 128 + 64 + lane];
    }

    f16x2 qi2[2], xx2[2], xy2[2], xz2[2];
#pragma unroll
    for (int s = 0; s < 2; ++s) {
        const int row = m0 + s * 16 + idx16;
        float fx, fy, fz, fq;
        if (MODE == 0) {
            const float* r = pc + ((size_t)b * NN + row) * 3;
            fx = r[0] * a0; fy = r[1] * a1; fz = r[2] * a2;
            fq = CWF * (fx * fx + fy * fy + fz * fz);
            if (wv == 0 && quad == 0) {
                float4 o; o.x = fx; o.y = fy; o.z = fz; o.w = fq;
                *(float4*)(Xs + ((size_t)p * NN + row) * 4) = o;
            }
        } else {
            float4 v = *(const float4*)(Xs + ((size_t)p * NN + row) * 4);
            fx = v.x; fy = v.y; fz = v.z; fq = v.w;
        }
        _Float16 q = (_Float16)(fq + NL2T);
        _Float16 x = (_Float16)(C2F * fx);
        _Float16 y = (_Float16)(C2F * fy);
        _Float16 z = (_Float16)(C2F * fz);
        qi2[s] = (f16x2){q, q}; xx2[s] = (f16x2){x, x};
        xy2[s] = (f16x2){y, y}; xz2[s] = (f16x2){z, z};
    }
    const f16x2 SC2  = (f16x2){(_Float16)32768.f, (_Float16)32768.f};
    const f16x2 ONE2 = (f16x2){(_Float16)1.f, (_Float16)1.f};
    const f16x2 ZER2 = (f16x2){(_Float16)0.f, (_Float16)0.f};

    const _Float16* bp = cur + ((size_t)p * 16 + idx16) * NN + wv * 256 + quad * 8;
    f32x4 acc[2] = {{0.f,0.f,0.f,0.f},{0.f,0.f,0.f,0.f}};

#pragma unroll
    for (int kc = 0; kc < 8; ++kc) {
        const int pb = wv * 128 + kc * 16 + quad * 4;  // j-pair entry base
        union { f16x2 h2[4]; half8 h8; } bfu;
        if (MODE != 0) {
            bool ld;
            if (MODE == 3)                   ld = (idx16 != 3);   // row3 == 0
            else if (MODE == 1 || MODE == 2) ld = (idx16 < 3);
            else                             ld = (idx16 >= 4);   // 4,5
            if (ld) bfu.h8 = *(const half8*)(bp + kc * 32);
            else {
#pragma unroll
                for (int z = 0; z < 4; ++z) bfu.h2[z] = ZER2;
            }
        }
        union { f16x2 h2[4]; half8 h8; } af[2];
#pragma unroll
        for (int jp = 0; jp < 4; ++jp) {
            union { float4 f; f16x2 h[4]; } e;
            e.f = ((const float4*)smem)[pb + jp];      // {x2,y2,z2,q2} for 2 j
            if (MODE == 0) {                           // B = {x,y,z,1,0..} in-reg
                bfu.h2[jp] = (idx16 == 0) ? e.h[0]
                           : (idx16 == 1) ? e.h[1]
                           : (idx16 == 2) ? e.h[2]
                           : (idx16 == 3) ? ONE2 : ZER2;
            }
#pragma unroll
            for (int s = 0; s < 2; ++s) {
                f16x2 tv = qi2[s] + e.h[3];
                tv = __builtin_elementwise_fma(xx2[s], e.h[0], tv);
                tv = __builtin_elementwise_fma(xy2[s], e.h[1], tv);
                tv = __builtin_elementwise_fma(xz2[s], e.h[2], tv);
                // threshold folded into exp arg: t'<0 -> arg<=-24 -> exp2 = 0
                f16x2 u = __builtin_elementwise_min(tv, tv * SC2);
                af[s].h2[jp] = __ocml_exp2_2f16(u);    // = 10*w (2^3.32 fold)
            }
        }
#pragma unroll
        for (int s = 0; s < 2; ++s)
            acc[s] = __builtin_amdgcn_mfma_f32_16x16x32_f16(af[s].h8, bfu.h8, acc[s], 0, 0, 0);
    }

    // ---- epilogue (coalesced mapping: n = tid>>5, row = m0 + (tid&31)) ----
    const int n  = tid >> 5;                        // output row of [16][NN]
    const int rr = tid & 31;                        // row within m-block
    const int s2 = rr >> 4, mloc = rr & 15;
    const int base = s2 * 256 + (mloc >> 2) * 64 + (mloc & 3);
    const int row = m0 + rr;
    float ihEff;
    if (MODE != 0) ihEff = 0.1f * ihd[p * NN + row];

#pragma unroll
    for (int s = 0; s < 2; ++s)
        *(f32x4*)&smem[4096 + wv * 512 + s * 256 + lane * 4] = acc[s];
    __syncthreads();

    float sum = 0.f;                               // = 10*(W@B)
#pragma unroll
    for (int g = 0; g < 8; ++g) sum += smem[4096 + g * 512 + base + n * 4];
    if (MODE == 0) {
        float deg10 = 0.f;                         // = 10*deg (col 3 = ones)
#pragma unroll
        for (int g = 0; g < 8; ++g) deg10 += smem[4096 + g * 512 + base + 12];
        float ih = 5.0f / deg10;                   // = 0.5/deg
        if (n == 3) ihd[p * NN + row] = ih;
        ihEff = 0.1f * ih;
    }
    float cv;
    if (MODE == 0) {
        cv = (n < 3) ? pc[((size_t)b * NN + row) * 3 + n] * alphas[(p & 3) * 3 + n] : 0.f;
    } else if (MODE == 1 || MODE == 2) {
        cv = (n < 3) ? (float)cur[((size_t)p * 16 + n) * NN + row] : 0.f;
    } else if (MODE == 3) {
        cv = (float)cur[((size_t)p * 16 + n) * NN + row];
    } else {                                       // 4, 5
        cv = (n >= 4) ? (float)cur[((size_t)p * 16 + n) * NN + row] : 0.f;
    }
    float o1v = 0.5f * cv + ihEff * sum;

    if (MODE == 0 || MODE == 1) {
        if (n < 3) {
            out[((size_t)p * 16 + n) * NN + row] = (_Float16)o1v;
            if (lvl) lvl[(((size_t)p * 5 + t) * 16 + n) * NN + row] = o1v;
        }
    } else if (MODE == 2) {
        // stash fresh t=8 (rows 0-2), then emit combined bank (row 3 = 0)
        if (n < 3) {
            lvl[(((size_t)p * 5 + t) * 16 + n) * NN + row] = o1v;
            smem[8192 + n * 32 + rr] = o1v;
        }
        __syncthreads();
        float oval = o1v;                          // n<3: t8; n==3: exact 0
        if (n >= 4) {                              // rows 4-15: U = |psi_jw|_c
            const int u = n - 4, jw = u / 3, c = u - 3 * jw;
            float a = (jw == 0) ? Xs[((size_t)p * NN + row) * 4 + c]
                                : LT1u[(((size_t)p * 5 + (jw - 1)) * 16 + c) * NN + row];
            float bb = (jw == 3) ? smem[8192 + c * 32 + rr]
                                 : LT1u[(((size_t)p * 5 + jw) * 16 + c) * NN + row];
            oval = fabsf(a - bb);
        }
        out[((size_t)p * 16 + n) * NN + row] = (_Float16)oval;
    } else if (MODE == 3) {
        out[((size_t)p * 16 + n) * NN + row] = (_Float16)o1v;
        if (lvl && (n >= 4 || (t == 3 && n < 3)))
            lvl[(((size_t)p * 5 + t) * 16 + n) * NN + row] = o1v;
    } else if (MODE == 4) {
        if (n >= 4) out[((size_t)p * 16 + n) * NN + row] = (_Float16)o1v;
    } else {                                       // MODE 5: fused reduction
        if (n >= 4) smem[8192 + (n - 4) * 32 + rr] = o1v;   // slot4 rows 4-15
        __syncthreads();
        if (tid < 384) {
            const int f = tid >> 3, g = tid & 7;            // 48 f x 8 thr
            const float* l1 = LT1u + (size_t)p * 5 * 16 * NN;
            const float* l2 = LT2r + (size_t)p * 5 * 16 * NN;
            float s = 0.f;
#pragma unroll
            for (int k = 0; k < 4; ++k) {
                const int m = m0 + g * 4 + k;
                float v;
                if (f < 3) {
                    v = l2[((size_t)3 * 16 + f) * NN + m];  // P^16 F (slot3 r0-2)
                } else if (f < 18) {
                    int j = (f - 3) / 3, c = (f - 3) % 3;
                    float a = (j == 0) ? Xs[((size_t)p * NN + m) * 4 + c]
                                       : l1[((size_t)(j - 1) * 16 + c) * NN + m];
                    float bb = (j < 4) ? l1[((size_t)j * 16 + c) * NN + m]
                                       : l2[((size_t)3 * 16 + c) * NN + m];
                    v = fabsf(a - bb);
                } else {
                    int gg = f - 18, j2, uc;
                    if (gg < 3)       { j2 = 1; uc = gg; }
                    else if (gg < 9)  { j2 = 2; uc = gg - 3; }
                    else if (gg < 18) { j2 = 3; uc = gg - 9; }
                    else              { j2 = 4; uc = gg - 18; }
                    float a = l2[((size_t)(j2 - 1) * 16 + uc + 4) * NN + m];
                    float bb = (j2 == 4) ? smem[8192 + uc * 32 + (g * 4 + k)]
                                         : l2[((size_t)j2 * 16 + uc + 4) * NN + m];
                    v = fabsf(a - bb);
                }
                s += v;
            }
#pragma unroll
            for (int off = 4; off > 0; off >>= 1) s += __shfl_down(s, off, 8);
            if (g == 0) atomicAdd(&fout[p * 48 + f], s * (1.0f / NN));
        }
    }
}

extern "C" void kernel_launch(void* const* d_in, const int* in_sizes, int n_in,
                              void* d_out, int out_size, void* d_ws, size_t ws_size,
                              hipStream_t stream) {
    const float* pc     = (const float*)d_in[0];
    const float* alphas = (const float*)d_in[1];
    float* outp = (float*)d_out;

    char* base = (char*)d_ws;
    size_t off = 0;
    auto carve = [&](size_t bytes) -> void* {
        void* r = base + off;
        off = (off + bytes + 255) & ~(size_t)255;
        return r;
    };
    float*     Xs  = (float*)carve((size_t)NPAIR * NN * 4 * sizeof(float));
    _Float16*  Xp  = (_Float16*)carve((size_t)NPAIR * 1024 * 8 * 2);
    float*     ihd = (float*)carve((size_t)NPAIR * NN * sizeof(float));
    _Float16*  pA  = (_Float16*)carve((size_t)NPAIR * 16 * NN * 2);
    _Float16*  pB  = (_Float16*)carve((size_t)NPAIR * 16 * NN * 2);
    float*     LT1 = (float*)carve((size_t)NPAIR * 5 * 16 * NN * sizeof(float));
    float*     LT2 = (float*)carve((size_t)NPAIR * 5 * 16 * NN * sizeof(float));

    dim3 gridA(NN / 32, NPAIR);   // 64 x 16 = 1024 blocks

    // step 1: fused init (Xs/Xp/out-zero) + apply (t=1 -> LT1 slot 0, ihd)
    apply_k<0><<<gridA, 512, 0, stream>>>(pc, alphas, Xs, Xp, ihd,
        nullptr, pA, LT1, 0, nullptr, nullptr, outp);
    const _Float16* c1 = pA;
    int slot = 1;

    // phase 1: bank1 steps 2..8 (t=2,4,8 -> LT1 slots 1..3); step 8 packs U
    // into rows 4-15 of its output (combined bank, row 3 = 0).
    for (int step = 2; step <= 8; ++step) {
        _Float16* o1 = (c1 == pA) ? pB : pA;
        bool sv = (step & (step - 1)) == 0;
        if (step == 8)
            apply_k<2><<<gridA, 512, 0, stream>>>(pc, alphas, Xs, Xp, ihd,
                c1, o1, LT1, 3, LT1, nullptr, nullptr);
        else
            apply_k<1><<<gridA, 512, 0, stream>>>(pc, alphas, Xs, Xp, ihd,
                c1, o1, sv ? LT1 : nullptr, slot, nullptr, nullptr, nullptr);
        if (sv) ++slot;
        c1 = o1;
    }

    // phase 2: combined bank, 16 steps. saves i=1,2,4,8 -> LT2 slots 0..3
    // (slot 3 rows 0-2 = bank1 t16 low-pass). i=9..15: rows 0-2 dead ->
    // trimmed. i=16: fused final reduction (atomicAdd into d_out).
    int slot2 = 0;
    for (int i = 1; i <= 16; ++i) {
        _Float16* o1 = (c1 == pA) ? pB : pA;
        if (i == 16) {
            apply_k<5><<<gridA, 512, 0, stream>>>(pc, alphas, Xs, Xp, ihd,
                c1, o1, nullptr, 4, LT1, LT2, outp);
        } else if (i <= 8) {
            bool sv = (i & (i - 1)) == 0;
            apply_k<3><<<gridA, 512, 0, stream>>>(pc, alphas, Xs, Xp, ihd,
                c1, o1, sv ? LT2 : nullptr, slot2, nullptr, nullptr, nullptr);
            if (sv) ++slot2;
        } else {
            apply_k<4><<<gridA, 512, 0, stream>>>(pc, alphas, Xs, Xp, ihd,
                c1, o1, nullptr, 0, nullptr, nullptr, nullptr);
        }
        c1 = o1;
    }
}

// Round 9
// 424.724 us; speedup vs baseline: 1.1270x; 1.0104x over previous
//
#include <hip/hip_runtime.h>
#include <hip/hip_bf16.h>

// PointCloudNetPersistencePrediction — round 28: VGPR-budget probe.
// Single variable vs R25 (423.3us best): __launch_bounds__(512,8->4).
// The ,8 bound caps VGPRs at 64; the eval body plausibly wants ~60-80 live
// regs (2x f32x4 acc + 8 bcast consts + bfu/af/e unions + addrs + staging)
// -> possible spills/remat that would be invisible to every structural
// change tried (barriers R23, traffic R25/R27, unroll R27, restructure R26).
// ,4 -> 128-VGPR cap, occupancy 4->2 blocks/CU (16 waves/CU, 4/SIMD; jp-ILP
// x 4 waves ~ 16 indep chains, still enough for LDS-latency hiding IF the
// kernel is issue-bound). Outcome disambiguates VGPR-starved (-15..30us)
// vs occupancy-bound (+20..50us). R27 extras reverted (neutral).
// MODE: 0=STEP1(fused init) 1=P1 2=P1+BUILDU 3=P2 4=P2TAIL 5=FUSEDRED

#define NN 2048
#define NPAIR 16

typedef _Float16 half8 __attribute__((ext_vector_type(8)));
typedef _Float16 f16x2 __attribute__((ext_vector_type(2)));
typedef float f32x4 __attribute__((ext_vector_type(4)));

extern "C" __device__ f16x2 __ocml_exp2_2f16(f16x2);   // packed v_exp_f16

#define C2F 0.28853900817779268f   //  0.2 * log2(e)
#define CWF -0.14426950408889634f  // -0.1 * log2(e)
#define NL2T 3.3219280948873623f   // -log2(0.1); qi' = qi + NL2T

// MODE: 0=STEP1(fused init), 1=P1, 2=P1+BUILDU, 3=P2, 4=P2TAIL, 5=FUSEDRED
template<int MODE>
__global__ __launch_bounds__(512, 4)
void apply_k(const float* __restrict__ pc, const float* __restrict__ alphas,
             float* __restrict__ Xs, _Float16* __restrict__ Xp,
             float* __restrict__ ihd,
             const _Float16* __restrict__ cur, _Float16* __restrict__ out,
             float* __restrict__ lvl, int t,
             const float* __restrict__ LT1u, const float* __restrict__ LT2r,
             float* __restrict__ fout) {
    // [0..4095]   : staged j-pair entries (1024 float4)
    // [4096..8191]: 8 waves x 512 MFMA partials
    // [8192..8575]: BUILDU stash (3x32) / FUSEDRED slot4 stash (12x32)
    __shared__ __align__(16) float smem[8576];
    const int tid  = threadIdx.x;
    const int lane = tid & 63;
    const int wv   = tid >> 6;                     // K-group 0..7
    const int p    = blockIdx.y;
    const int m0   = blockIdx.x * 32;
    const int idx16 = lane & 15, quad = lane >> 4;
    const int b = p >> 2;

    float a0, a1, a2;
    if (MODE == 0) {
        const int kk = p & 3;
        a0 = alphas[kk * 3 + 0]; a1 = alphas[kk * 3 + 1]; a2 = alphas[kk * 3 + 2];
        if (blockIdx.x == 0 && tid < 48) fout[p * 48 + tid] = 0.f;
        // per-wave slice: compute own 128 j-pair entries from pc*alphas
        float4* dst = (float4*)smem;
#pragma unroll
        for (int e = 0; e < 2; ++e) {
            const int idx = wv * 128 + e * 64 + lane;
            const float* r = pc + ((size_t)b * NN + idx * 2) * 3;  // 2 points, 6 floats
            float x0 = r[0] * a0, y0 = r[1] * a1, z0 = r[2] * a2;
            float x1 = r[3] * a0, y1 = r[4] * a1, z1 = r[5] * a2;
            float q0 = CWF * (x0 * x0 + y0 * y0 + z0 * z0);
            float q1 = CWF * (x1 * x1 + y1 * y1 + z1 * z1);
            union { float4 f; f16x2 h[4]; } ev;
            ev.h[0] = (f16x2){(_Float16)x0, (_Float16)x1};
            ev.h[1] = (f16x2){(_Float16)y0, (_Float16)y1};
            ev.h[2] = (f16x2){(_Float16)z0, (_Float16)z1};
            ev.h[3] = (f16x2){(_Float16)q0, (_Float16)q1};
            dst[idx] = ev.f;
            if (blockIdx.x == 0) ((float4*)Xp)[(size_t)p * 1024 + idx] = ev.f;
        }
    } else {
        // per-wave slice staging from global Xp (no barrier needed)
        const float4* src = (const float4*)(Xp + (size_t)p * 8192);
        float4* dst = (float4*)smem;
        dst[wv * 128 + lane]      = src[wv * 128 + lane];
        dst[wv * 128 + 64 + lane] = src[wv * 128 + 64 + lane];
    }

    f16x2 qi2[2], xx2[2], xy2[2], xz2[2];
#pragma unroll
    for (int s = 0; s < 2; ++s) {
        const int row = m0 + s * 16 + idx16;
        float fx, fy, fz, fq;
        if (MODE == 0) {
            const float* r = pc + ((size_t)b * NN + row) * 3;
            fx = r[0] * a0; fy = r[1] * a1; fz = r[2] * a2;
            fq = CWF * (fx * fx + fy * fy + fz * fz);
            if (wv == 0 && quad == 0) {
                float4 o; o.x = fx; o.y = fy; o.z = fz; o.w = fq;
                *(float4*)(Xs + ((size_t)p * NN + row) * 4) = o;
            }
        } else {
            float4 v = *(const float4*)(Xs + ((size_t)p * NN + row) * 4);
            fx = v.x; fy = v.y; fz = v.z; fq = v.w;
        }
        _Float16 q = (_Float16)(fq + NL2T);
        _Float16 x = (_Float16)(C2F * fx);
        _Float16 y = (_Float16)(C2F * fy);
        _Float16 z = (_Float16)(C2F * fz);
        qi2[s] = (f16x2){q, q}; xx2[s] = (f16x2){x, x};
        xy2[s] = (f16x2){y, y}; xz2[s] = (f16x2){z, z};
    }
    const f16x2 SC2  = (f16x2){(_Float16)32768.f, (_Float16)32768.f};
    const f16x2 ONE2 = (f16x2){(_Float16)1.f, (_Float16)1.f};
    const f16x2 ZER2 = (f16x2){(_Float16)0.f, (_Float16)0.f};

    const _Float16* bp = cur + ((size_t)p * 16 + idx16) * NN + wv * 256 + quad * 8;
    f32x4 acc[2] = {{0.f,0.f,0.f,0.f},{0.f,0.f,0.f,0.f}};

    for (int kc = 0; kc < 8; ++kc) {
        const int pb = wv * 128 + kc * 16 + quad * 4;  // j-pair entry base
        union { f16x2 h2[4]; half8 h8; } bfu;
        if (MODE != 0) {
            bool ld;
            if (MODE == 3)                   ld = true;
            else if (MODE == 1 || MODE == 2) ld = (idx16 < 3);
            else                             ld = (idx16 >= 4);   // 4,5
            if (ld) bfu.h8 = *(const half8*)(bp + kc * 32);
            else {
#pragma unroll
                for (int z = 0; z < 4; ++z) bfu.h2[z] = ZER2;
            }
        }
        union { f16x2 h2[4]; half8 h8; } af[2];
#pragma unroll
        for (int jp = 0; jp < 4; ++jp) {
            union { float4 f; f16x2 h[4]; } e;
            e.f = ((const float4*)smem)[pb + jp];      // {x2,y2,z2,q2} for 2 j
            if (MODE == 0) {                           // B = {x,y,z,1,0..} in-reg
                bfu.h2[jp] = (idx16 == 0) ? e.h[0]
                           : (idx16 == 1) ? e.h[1]
                           : (idx16 == 2) ? e.h[2]
                           : (idx16 == 3) ? ONE2 : ZER2;
            }
#pragma unroll
            for (int s = 0; s < 2; ++s) {
                f16x2 tv = qi2[s] + e.h[3];
                tv = __builtin_elementwise_fma(xx2[s], e.h[0], tv);
                tv = __builtin_elementwise_fma(xy2[s], e.h[1], tv);
                tv = __builtin_elementwise_fma(xz2[s], e.h[2], tv);
                // threshold folded into exp arg: t'<0 -> arg<=-24 -> exp2 = 0
                f16x2 u = __builtin_elementwise_min(tv, tv * SC2);
                af[s].h2[jp] = __ocml_exp2_2f16(u);    // = 10*w (2^3.32 fold)
            }
        }
#pragma unroll
        for (int s = 0; s < 2; ++s)
            acc[s] = __builtin_amdgcn_mfma_f32_16x16x32_f16(af[s].h8, bfu.h8, acc[s], 0, 0, 0);
    }

    // ---- epilogue (coalesced mapping: n = tid>>5, row = m0 + (tid&31)) ----
    const int n  = tid >> 5;                        // output row of [16][NN]
    const int rr = tid & 31;                        // row within m-block
    const int s2 = rr >> 4, mloc = rr & 15;
    const int base = s2 * 256 + (mloc >> 2) * 64 + (mloc & 3);
    const int row = m0 + rr;
    float ihEff;
    if (MODE != 0) ihEff = 0.1f * ihd[p * NN + row];

#pragma unroll
    for (int s = 0; s < 2; ++s)
        *(f32x4*)&smem[4096 + wv * 512 + s * 256 + lane * 4] = acc[s];
    __syncthreads();

    float sum = 0.f;                               // = 10*(W@B)
#pragma unroll
    for (int g = 0; g < 8; ++g) sum += smem[4096 + g * 512 + base + n * 4];
    if (MODE == 0) {
        float deg10 = 0.f;                         // = 10*deg (col 3 = ones)
#pragma unroll
        for (int g = 0; g < 8; ++g) deg10 += smem[4096 + g * 512 + base + 12];
        float ih = 5.0f / deg10;                   // = 0.5/deg
        if (n == 3) ihd[p * NN + row] = ih;
        ihEff = 0.1f * ih;
    }
    float cv;
    if (MODE == 0) {
        cv = (n < 3) ? pc[((size_t)b * NN + row) * 3 + n] * alphas[(p & 3) * 3 + n] : 0.f;
    } else if (MODE == 1 || MODE == 2) {
        cv = (n < 3) ? (float)cur[((size_t)p * 16 + n) * NN + row] : 0.f;
    } else if (MODE == 3) {
        cv = (float)cur[((size_t)p * 16 + n) * NN + row];
    } else {                                       // 4, 5
        cv = (n >= 4) ? (float)cur[((size_t)p * 16 + n) * NN + row] : 0.f;
    }
    float o1v = 0.5f * cv + ihEff * sum;

    if (MODE == 0 || MODE == 1) {
        if (n < 3) {
            out[((size_t)p * 16 + n) * NN + row] = (_Float16)o1v;
            if (lvl) lvl[(((size_t)p * 5 + t) * 16 + n) * NN + row] = o1v;
        }
    } else if (MODE == 2) {
        // stash fresh t=8 (rows 0-2), then emit combined bank (row 3 = 0)
        if (n < 3) {
            lvl[(((size_t)p * 5 + t) * 16 + n) * NN + row] = o1v;
            smem[8192 + n * 32 + rr] = o1v;
        }
        __syncthreads();
        float oval = o1v;                          // n<3: t8; n==3: exact 0
        if (n >= 4) {                              // rows 4-15: U = |psi_jw|_c
            const int u = n - 4, jw = u / 3, c = u - 3 * jw;
            float a = (jw == 0) ? Xs[((size_t)p * NN + row) * 4 + c]
                                : LT1u[(((size_t)p * 5 + (jw - 1)) * 16 + c) * NN + row];
            float bb = (jw == 3) ? smem[8192 + c * 32 + rr]
                                 : LT1u[(((size_t)p * 5 + jw) * 16 + c) * NN + row];
            oval = fabsf(a - bb);
        }
        out[((size_t)p * 16 + n) * NN + row] = (_Float16)oval;
    } else if (MODE == 3) {
        out[((size_t)p * 16 + n) * NN + row] = (_Float16)o1v;
        if (lvl && (n >= 4 || (t == 3 && n < 3)))
            lvl[(((size_t)p * 5 + t) * 16 + n) * NN + row] = o1v;
    } else if (MODE == 4) {
        if (n >= 4) out[((size_t)p * 16 + n) * NN + row] = (_Float16)o1v;
    } else {                                       // MODE 5: fused reduction
        if (n >= 4) smem[8192 + (n - 4) * 32 + rr] = o1v;   // slot4 rows 4-15
        __syncthreads();
        if (tid < 384) {
            const int f = tid >> 3, g = tid & 7;            // 48 f x 8 thr
            const float* l1 = LT1u + (size_t)p * 5 * 16 * NN;
            const float* l2 = LT2r + (size_t)p * 5 * 16 * NN;
            float s = 0.f;
#pragma unroll
            for (int k = 0; k < 4; ++k) {
                const int m = m0 + g * 4 + k;
                float v;
                if (f < 3) {
                    v = l2[((size_t)3 * 16 + f) * NN + m];  // P^16 F (slot3 r0-2)
                } else if (f < 18) {
                    int j = (f - 3) / 3, c = (f - 3) % 3;
                    float a = (j == 0) ? Xs[((size_t)p * NN + m) * 4 + c]
                                       : l1[((size_t)(j - 1) * 16 + c) * NN + m];
                    float bb = (j < 4) ? l1[((size_t)j * 16 + c) * NN + m]
                                       : l2[((size_t)3 * 16 + c) * NN + m];
                    v = fabsf(a - bb);
                } else {
                    int gg = f - 18, j2, uc;
                    if (gg < 3)       { j2 = 1; uc = gg; }
                    else if (gg < 9)  { j2 = 2; uc = gg - 3; }
                    else if (gg < 18) { j2 = 3; uc = gg - 9; }
                    else              { j2 = 4; uc = gg - 18; }
                    float a = l2[((size_t)(j2 - 1) * 16 + uc + 4) * NN + m];
                    float bb = (j2 == 4) ? smem[8192 + uc * 32 + (g * 4 + k)]
                                         : l2[((size_t)j2 * 16 + uc + 4) * NN + m];
                    v = fabsf(a - bb);
                }
                s += v;
            }
#pragma unroll
            for (int off = 4; off > 0; off >>= 1) s += __shfl_down(s, off, 8);
            if (g == 0) atomicAdd(&fout[p * 48 + f], s * (1.0f / NN));
        }
    }
}

extern "C" void kernel_launch(void* const* d_in, const int* in_sizes, int n_in,
                              void* d_out, int out_size, void* d_ws, size_t ws_size,
                              hipStream_t stream) {
    const float* pc     = (const float*)d_in[0];
    const float* alphas = (const float*)d_in[1];
    float* outp = (float*)d_out;

    char* base = (char*)d_ws;
    size_t off = 0;
    auto carve = [&](size_t bytes) -> void* {
        void* r = base + off;
        off = (off + bytes + 255) & ~(size_t)255;
        return r;
    };
    float*     Xs  = (float*)carve((size_t)NPAIR * NN * 4 * sizeof(float));
    _Float16*  Xp  = (_Float16*)carve((size_t)NPAIR * 1024 * 8 * 2);
    float*     ihd = (float*)carve((size_t)NPAIR * NN * sizeof(float));
    _Float16*  pA  = (_Float16*)carve((size_t)NPAIR * 16 * NN * 2);
    _Float16*  pB  = (_Float16*)carve((size_t)NPAIR * 16 * NN * 2);
    float*     LT1 = (float*)carve((size_t)NPAIR * 5 * 16 * NN * sizeof(float));
    float*     LT2 = (float*)carve((size_t)NPAIR * 5 * 16 * NN * sizeof(float));

    dim3 gridA(NN / 32, NPAIR);   // 64 x 16 = 1024 blocks

    // step 1: fused init (Xs/Xp/out-zero) + apply (t=1 -> LT1 slot 0, ihd)
    apply_k<0><<<gridA, 512, 0, stream>>>(pc, alphas, Xs, Xp, ihd,
        nullptr, pA, LT1, 0, nullptr, nullptr, outp);
    const _Float16* c1 = pA;
    int slot = 1;

    // phase 1: bank1 steps 2..8 (t=2,4,8 -> LT1 slots 1..3); step 8 packs U
    // into rows 4-15 of its output (combined bank, row 3 = 0).
    for (int step = 2; step <= 8; ++step) {
        _Float16* o1 = (c1 == pA) ? pB : pA;
        bool sv = (step & (step - 1)) == 0;
        if (step == 8)
            apply_k<2><<<gridA, 512, 0, stream>>>(pc, alphas, Xs, Xp, ihd,
                c1, o1, LT1, 3, LT1, nullptr, nullptr);
        else
            apply_k<1><<<gridA, 512, 0, stream>>>(pc, alphas, Xs, Xp, ihd,
                c1, o1, sv ? LT1 : nullptr, slot, nullptr, nullptr, nullptr);
        if (sv) ++slot;
        c1 = o1;
    }

    // phase 2: combined bank, 16 steps. saves i=1,2,4,8 -> LT2 slots 0..3
    // (slot 3 rows 0-2 = bank1 t16 low-pass). i=9..15: rows 0-2 dead ->
    // trimmed. i=16: fused final reduction (atomicAdd into d_out).
    int slot2 = 0;
    for (int i = 1; i <= 16; ++i) {
        _Float16* o1 = (c1 == pA) ? pB : pA;
        if (i == 16) {
            apply_k<5><<<gridA, 512, 0, stream>>>(pc, alphas, Xs, Xp, ihd,
                c1, o1, nullptr, 4, LT1, LT2, outp);
        } else if (i <= 8) {
            bool sv = (i & (i - 1)) == 0;
            apply_k<3><<<gridA, 512, 0, stream>>>(pc, alphas, Xs, Xp, ihd,
                c1, o1, sv ? LT2 : nullptr, slot2, nullptr, nullptr, nullptr);
            if (sv) ++slot2;
        } else {
            apply_k<4><<<gridA, 512, 0, stream>>>(pc, alphas, Xs, Xp, ihd,
                c1, o1, nullptr, 0, nullptr, nullptr, nullptr);
        }
        c1 = o1;
    }
}